// Round 13
// baseline (517.464 us; speedup 1.0000x reference)
//
#include <hip/hip_runtime.h>
#include <hip/hip_bf16.h>

typedef unsigned short u16;   // bf16 bits
typedef __attribute__((ext_vector_type(8))) short short8v;   // 8 bf16 (4 VGPRs)
typedef __attribute__((ext_vector_type(4))) float f32x4;
typedef union { short8v v; uint u[4]; } pack8;

__device__ __forceinline__ float bu2f(u16 u) {
    return __uint_as_float(((unsigned)u) << 16);
}
__device__ __forceinline__ u16 f2bu(float f) {   // RNE f32->bf16
    unsigned u = __float_as_uint(f);
    u += 0x7fffu + ((u >> 16) & 1u);
    return (u16)(u >> 16);
}
__device__ __forceinline__ uint pk2(float a, float b) {
    return (uint)f2bu(a) | ((uint)f2bu(b) << 16);
}

// ---------------------------------------------------------------------------
// K-repack: all weights -> MFMA-friendly bf16 layouts in ws.
//  w1p  [32][72]: k = kh*16 + kw*3 + c (zeros elsewhere)         conv1
//  s2wp [96][72]: rows 0-47 W_lin hi, 48-95 W_lin lo; k<48 valid stage2
//  w2p  [64][296]: k = tap*32 + ic                               conv2
//  w3p  [128][584]: k = tap*64 + ic                              conv3
// ---------------------------------------------------------------------------
__global__ __launch_bounds__(256) void k_repack(
    const float* __restrict__ Wlin, const float* __restrict__ c1w,
    const float* __restrict__ c2w, const float* __restrict__ c3w,
    u16* __restrict__ w1p, u16* __restrict__ s2wp,
    u16* __restrict__ w2p, u16* __restrict__ w3p)
{
    int i = blockIdx.x * 256 + threadIdx.x;
    if (i < 32 * 72) {
        int oc = i / 72, k = i - oc * 72;
        int kh = k >> 4, e = k & 15;
        u16 v = 0;
        if (kh < 3 && e < 9) {
            int kw = e / 3, c = e - kw * 3;
            v = f2bu(c1w[((oc * 3 + c) * 3 + kh) * 3 + kw]);
        }
        w1p[i] = v;
    }
    if (i < 96 * 72) {
        int r = i / 72, k = i - r * 72;
        u16 v = 0;
        if (k < 48) {
            int o = r % 48;
            float w = Wlin[o * 48 + k];
            u16 hi = f2bu(w);
            v = (r < 48) ? hi : f2bu(w - bu2f(hi));
        }
        s2wp[i] = v;
    }
    if (i < 64 * 288) {
        int oc = i / 288, r = i - oc * 288;
        int tap = r >> 5, ic = r & 31;
        w2p[oc * 296 + r] = f2bu(c2w[(oc * 32 + ic) * 9 + tap]);
    }
    if (i < 128 * 576) {
        int oc = i / 576, r = i - oc * 576;
        int tap = r >> 6, ic = r & 63;
        w3p[oc * 584 + r] = f2bu(c3w[(oc * 64 + ic) * 9 + tap]);
    }
}

// ---------------------------------------------------------------------------
// K-front: stage2 (MFMA, W split hi/lo) + conv1 (MFMA, im2col-free) fused.
// ---------------------------------------------------------------------------
#define IMG_E 0
#define IMG_O 3488
#define XB    6976
#define S2W   11584
#define W1L   18496
#define LDSZ  20800

__global__ __launch_bounds__(256) void k_front(
    const float* __restrict__ x, const u16* __restrict__ s2wp,
    const u16* __restrict__ w1p, const float* __restrict__ cb,
    const int* __restrict__ stage, u16* __restrict__ o1)
{
    __shared__ __align__(16) u16 lds[LDSZ];
    const int b = blockIdx.x, t = threadIdx.x;
    const int wv = t >> 6, lane = t & 63, lr = lane & 15, q = lane >> 4;

    uint* zi = (uint*)lds;
    for (int i = t; i < 3488; i += 256) zi[i] = 0u;
    for (int i = t; i < 864; i += 256)
        *(short8v*)(&lds[S2W + i * 8]) = *(const short8v*)(&s2wp[i * 8]);
    for (int i = t; i < 288; i += 256)
        *(short8v*)(&lds[W1L + i * 8]) = *(const short8v*)(&w1p[i * 8]);

    const int sv = stage[0];
    if (sv == 2) {
        {
            const int n = t >> 2, ir = t & 3;
            const float* xp = x + (size_t)b * 3072 + (((n >> 3) * 4 + ir) * 96 + (n & 7) * 12);
            const float4 va = ((const float4*)xp)[0];
            const float4 vb = ((const float4*)xp)[1];
            const float4 vc = ((const float4*)xp)[2];
            uint* dst = (uint*)&lds[XB + n * 72 + ir * 12];
            dst[0] = pk2(va.x, va.y); dst[1] = pk2(va.z, va.w);
            dst[2] = pk2(vb.x, vb.y); dst[3] = pk2(vb.z, vb.w);
            dst[4] = pk2(vc.x, vc.y); dst[5] = pk2(vc.z, vc.w);
            if (ir < 2) {
                uint* z2 = (uint*)&lds[XB + n * 72 + 48 + ir * 8];
                z2[0] = 0u; z2[1] = 0u; z2[2] = 0u; z2[3] = 0u;
            }
        }
        __syncthreads();
        short8v a0 = *(const short8v*)&lds[XB + (wv * 16 + lr) * 72 + q * 8];
        short8v a1 = *(const short8v*)&lds[XB + (wv * 16 + lr) * 72 + 32 + q * 8];
        f32x4 y[3];
        #pragma unroll
        for (int nf = 0; nf < 3; ++nf) {
            y[nf] = (f32x4){0.f, 0.f, 0.f, 0.f};
            short8v bh0 = *(const short8v*)&lds[S2W + (nf * 16 + lr) * 72 + q * 8];
            short8v bh1 = *(const short8v*)&lds[S2W + (nf * 16 + lr) * 72 + 32 + q * 8];
            short8v bl0 = *(const short8v*)&lds[S2W + (48 + nf * 16 + lr) * 72 + q * 8];
            short8v bl1 = *(const short8v*)&lds[S2W + (48 + nf * 16 + lr) * 72 + 32 + q * 8];
            y[nf] = __builtin_amdgcn_mfma_f32_16x16x32_bf16(a0, bh0, y[nf], 0, 0, 0);
            y[nf] = __builtin_amdgcn_mfma_f32_16x16x32_bf16(a1, bh1, y[nf], 0, 0, 0);
            y[nf] = __builtin_amdgcn_mfma_f32_16x16x32_bf16(a0, bl0, y[nf], 0, 0, 0);
            y[nf] = __builtin_amdgcn_mfma_f32_16x16x32_bf16(a1, bl1, y[nf], 0, 0, 0);
        }
        __syncthreads();
        #pragma unroll
        for (int nf = 0; nf < 3; ++nf)
            #pragma unroll
            for (int r = 0; r < 4; ++r) {
                int n2 = wv * 16 + q * 4 + r;
                int o  = nf * 16 + lr;
                int ir = o / 12, rm = o - ir * 12;
                int jc = rm / 3, c = rm - jc * 3;
                int hh = (n2 >> 3) * 4 + ir, ww = (n2 & 7) * 4 + jc;
                int e  = ((hh + 1) * 34 + (ww + 1)) * 3 + c;
                u16 val = f2bu(y[nf][r]);
                lds[IMG_E + e] = val;
                lds[IMG_O + e - 1] = val;
            }
    } else {
        __syncthreads();
        for (int e = t; e < 3072; e += 256) {
            int hh = e / 96, rm = e - hh * 96;
            int ww = rm / 3, c = rm - ww * 3;
            u16 val = f2bu(x[(size_t)b * 3072 + e]);
            int ii = ((hh + 1) * 34 + (ww + 1)) * 3 + c;
            lds[IMG_E + ii] = val;
            lds[IMG_O + ii - 1] = val;
        }
    }
    __syncthreads();

    short8v wf[2][2];
    #pragma unroll
    for (int nf = 0; nf < 2; ++nf)
        #pragma unroll
        for (int ks = 0; ks < 2; ++ks)
            wf[nf][ks] = *(const short8v*)&lds[W1L + (nf * 16 + lr) * 72 + ks * 32 + q * 8];
    const float bias[2] = {cb[lr], cb[16 + lr]};
    u16* op = o1 + (size_t)b * 8192;

    #pragma unroll
    for (int mc = 0; mc < 4; ++mc) {
        f32x4 acc[4][2];
        #pragma unroll
        for (int mi = 0; mi < 4; ++mi)
            #pragma unroll
            for (int nf = 0; nf < 2; ++nf) acc[mi][nf] = (f32x4){0.f, 0.f, 0.f, 0.f};
        #pragma unroll
        for (int mi = 0; mi < 4; ++mi) {
            const int p = wv * 256 + (mc * 4 + mi) * 16 + lr;
            const int ph = p >> 5, pw = p & 31;
            #pragma unroll
            for (int ks = 0; ks < 2; ++ks) {
                const int r = ks ? 2 : (q >> 1);
                const int a = 3 * ((ph + r) * 34 + pw) + (q & 1) * 8;
                const uint* sp = (a & 1) ? (const uint*)&lds[IMG_O + a - 1]
                                         : (const uint*)&lds[IMG_E + a];
                pack8 pk;
                pk.u[0] = sp[0]; pk.u[1] = sp[1]; pk.u[2] = sp[2]; pk.u[3] = sp[3];
                acc[mi][0] = __builtin_amdgcn_mfma_f32_16x16x32_bf16(pk.v, wf[0][ks], acc[mi][0], 0, 0, 0);
                acc[mi][1] = __builtin_amdgcn_mfma_f32_16x16x32_bf16(pk.v, wf[1][ks], acc[mi][1], 0, 0, 0);
            }
        }
        #pragma unroll
        for (int pr = 0; pr < 2; ++pr)
            #pragma unroll
            for (int nf = 0; nf < 2; ++nf) {
                const float bb = bias[nf];
                #pragma unroll
                for (int j = 0; j < 2; ++j) {
                    float v = fmaxf(acc[pr][nf][2 * j] + bb, 0.f);
                    v = fmaxf(v, fmaxf(acc[pr][nf][2 * j + 1] + bb, 0.f));
                    v = fmaxf(v, fmaxf(acc[pr + 2][nf][2 * j] + bb, 0.f));
                    v = fmaxf(v, fmaxf(acc[pr + 2][nf][2 * j + 1] + bb, 0.f));
                    const int hq = wv * 4 + mc, wq = pr * 8 + q * 2 + j;
                    op[(hq * 16 + wq) * 32 + nf * 16 + lr] = f2bu(v);
                }
            }
    }
}

// ---------------------------------------------------------------------------
// K-conv23 v6: fused conv2+conv3, WG = ONE image, cooperative per-step B
// staging in LDS. r8-r12 evidence: ~1700 cy/K-step dominated by per-wave
// global B-load latency (4 waves load IDENTICAL conv2 B rows). Fix: all 256
// threads stage the next step's B-tile global->reg->LDS, double-buffered,
// one barrier per step; waves read B via ds_read_b128 (padded strides,
// <=2-way conflicts). 4x fewer global loads; B off the latency path.
// LDS (u16): in3 [100][64] swz @0 | in2 [18][18][40] @6400 | wb2 2x[64][40]
// @19360 ; conv3 reuses in2+wb2 region for wb3 2x[128][68] @6400. 48.96 KB.
// No launch bound (r7/r12 lessons). Halo-only zeroing.
// ---------------------------------------------------------------------------
#define IN3 0
#define IN2 6400
#define WB2 19360
#define WB3 6400
#define LDS_N 24480
__global__ __launch_bounds__(256) void k_conv23(
    const u16* __restrict__ o1, const u16* __restrict__ w2p,
    const float* __restrict__ c2b, const u16* __restrict__ w3p,
    const float* __restrict__ c3b, u16* __restrict__ o3)
{
    __shared__ __align__(16) u16 lds[LDS_N];
    const int b = blockIdx.x, t = threadIdx.x;
    const int wv = t >> 6, lane = t & 63, lr = lane & 15, q = lane >> 4;
    uint* z32 = (uint*)lds;

    // ---- halo-only zeroing ----
    for (int i = t; i < 320; i += 256) { z32[i] = 0u; z32[2880 + i] = 0u; }   // in3 rows 0-9,90-99
    for (int j = t; j < 1024; j += 256) {                                     // in3 cols 0,9
        int r = 10 + (j >> 6) * 10 + ((j >> 5) & 1) * 9;
        z32[r * 32 + (j & 31)] = 0u;
    }
    {
        const int B2 = IN2 / 2;                                               // in2 halo
        for (int i = t; i < 360; i += 256) { z32[B2 + i] = 0u; z32[B2 + 6120 + i] = 0u; }
        for (int j = t; j < 640; j += 256) {
            int h = 1 + j / 40;
            int w = ((j / 20) & 1) * 17;
            z32[B2 + (h * 18 + w) * 20 + (j % 20)] = 0u;
        }
    }
    // ---- stage image into in2 ----
    {
        const u16* ip = o1 + (size_t)b * 8192;
        #pragma unroll
        for (int e4 = 0; e4 < 4; ++e4) {
            int e = e4 * 256 + t;
            int ic8 = e & 3, w = (e >> 2) & 15, h = e >> 6;
            *(short8v*)(&lds[IN2 + ((h + 1) * 18 + (w + 1)) * 40 + ic8 * 8]) =
                *(const short8v*)(&ip[e * 8]);
        }
    }
    // ---- conv2 B prologue: stage step 0, preload step 1 ----
    const int oc_w = t >> 2, qc_w = t & 3;
    const u16* wsrc2 = w2p + oc_w * 296 + qc_w * 8;
    {
        short8v v0 = *(const short8v*)(wsrc2 + 0);
        *(short8v*)(&lds[WB2 + oc_w * 40 + qc_w * 8]) = v0;
    }
    short8v wreg = *(const short8v*)(wsrc2 + 32);
    __syncthreads();

    // ---------------- conv2 phase ----------------
    {
        f32x4 acc[4][4];
        #pragma unroll
        for (int m = 0; m < 4; ++m)
            #pragma unroll
            for (int n = 0; n < 4; ++n) acc[m][n] = (f32x4){0.f, 0.f, 0.f, 0.f};

        #pragma unroll
        for (int s = 0; s < 9; ++s) {
            if (s > 0) __syncthreads();
            if (s + 1 < 9) {
                *(short8v*)(&lds[WB2 + ((s + 1) & 1) * 2560 + oc_w * 40 + qc_w * 8]) = wreg;
                if (s + 2 < 9) wreg = *(const short8v*)(wsrc2 + (s + 2) * 32);
            }
            const int kh = s / 3, kw = s - kh * 3;
            const u16* wb = &lds[WB2 + (s & 1) * 2560];
            short8v af[4], bf[4];
            #pragma unroll
            for (int m = 0; m < 4; ++m)
                af[m] = *(const short8v*)(&lds[IN2 + ((wv * 4 + m + kh) * 18 + lr + kw) * 40 + q * 8]);
            #pragma unroll
            for (int n = 0; n < 4; ++n)
                bf[n] = *(const short8v*)(&wb[(n * 16 + lr) * 40 + q * 8]);
            #pragma unroll
            for (int m = 0; m < 4; ++m)
                #pragma unroll
                for (int n = 0; n < 4; ++n)
                    acc[m][n] = __builtin_amdgcn_mfma_f32_16x16x32_bf16(af[m], bf[n], acc[m][n], 0, 0, 0);
        }
        // epilogue: bias+relu+pool -> in3 (swizzled), halo stays zero
        #pragma unroll
        for (int n = 0; n < 4; ++n) {
            float bias = c2b[n * 16 + lr];
            #pragma unroll
            for (int mp = 0; mp < 2; ++mp) {
                #pragma unroll
                for (int p = 0; p < 2; ++p) {
                    float v = fmaxf(acc[2 * mp][n][2 * p] + bias, 0.f);
                    v = fmaxf(v, fmaxf(acc[2 * mp][n][2 * p + 1] + bias, 0.f));
                    v = fmaxf(v, fmaxf(acc[2 * mp + 1][n][2 * p] + bias, 0.f));
                    v = fmaxf(v, fmaxf(acc[2 * mp + 1][n][2 * p + 1] + bias, 0.f));
                    int hq = wv * 2 + mp, wq = 2 * q + p;
                    int posW = (hq + 1) * 10 + (wq + 1);
                    int oc = n * 16 + lr;
                    lds[IN3 + posW * 64 + (oc ^ ((posW & 7) << 3))] = f2bu(v);
                }
            }
        }
    }
    __syncthreads();                      // in3 complete; in2/wb2 dead

    // ---- conv3 B prologue: stage tap 0 into wb3[0], preload tap 1 ----
    const int row3 = t >> 1, hf3 = t & 1;
    const u16* wsrc3 = w3p + row3 * 584 + hf3 * 32;
    {
        #pragma unroll
        for (int i = 0; i < 4; ++i) {
            short8v v = *(const short8v*)(wsrc3 + i * 8);
            *(short8v*)(&lds[WB3 + row3 * 68 + hf3 * 32 + i * 8]) = v;
        }
    }
    short8v w3r0 = *(const short8v*)(wsrc3 + 64 + 0);
    short8v w3r1 = *(const short8v*)(wsrc3 + 64 + 8);
    short8v w3r2 = *(const short8v*)(wsrc3 + 64 + 16);
    short8v w3r3 = *(const short8v*)(wsrc3 + 64 + 24);
    __syncthreads();

    // ---------------- conv3 phase: wave wv -> oc block wv*32 ----------------
    {
        const int ocb = wv * 32;
        const int hA = lr >> 3, wA = lr & 7;

        f32x4 acc3[4][2];
        #pragma unroll
        for (int m = 0; m < 4; ++m)
            #pragma unroll
            for (int n = 0; n < 2; ++n) acc3[m][n] = (f32x4){0.f, 0.f, 0.f, 0.f};

        #pragma unroll
        for (int T = 0; T < 9; ++T) {
            if (T > 0) __syncthreads();
            if (T + 1 < 9) {
                u16* wd = &lds[WB3 + ((T + 1) & 1) * 8704 + row3 * 68 + hf3 * 32];
                *(short8v*)(wd + 0)  = w3r0;
                *(short8v*)(wd + 8)  = w3r1;
                *(short8v*)(wd + 16) = w3r2;
                *(short8v*)(wd + 24) = w3r3;
                if (T + 2 < 9) {
                    const u16* gs = wsrc3 + (T + 2) * 64;
                    w3r0 = *(const short8v*)(gs + 0);
                    w3r1 = *(const short8v*)(gs + 8);
                    w3r2 = *(const short8v*)(gs + 16);
                    w3r3 = *(const short8v*)(gs + 24);
                }
            }
            const int kh = T / 3, kw = T - kh * 3;
            const u16* wbf = &lds[WB3 + (T & 1) * 8704];
            #pragma unroll
            for (int half = 0; half < 2; ++half) {
                short8v br[2], a3[4];
                #pragma unroll
                for (int n = 0; n < 2; ++n)
                    br[n] = *(const short8v*)(&wbf[(ocb + n * 16 + lr) * 68 + half * 32 + q * 8]);
                #pragma unroll
                for (int m = 0; m < 4; ++m) {
                    int posR = (m * 2 + hA + kh) * 10 + wA + kw;
                    int sl = (half * 32 + q * 8) ^ ((posR & 7) << 3);
                    a3[m] = *(const short8v*)(&lds[IN3 + posR * 64 + sl]);
                }
                #pragma unroll
                for (int m = 0; m < 4; ++m)
                    #pragma unroll
                    for (int n = 0; n < 2; ++n)
                        acc3[m][n] = __builtin_amdgcn_mfma_f32_16x16x32_bf16(a3[m], br[n], acc3[m][n], 0, 0, 0);
            }
        }
        #pragma unroll
        for (int n = 0; n < 2; ++n) {
            float bias = c3b[ocb + n * 16 + lr];
            #pragma unroll
            for (int m = 0; m < 4; ++m) {
                #pragma unroll
                for (int p = 0; p < 2; ++p) {
                    float v = fmaxf(acc3[m][n][2 * p] + bias, 0.f);
                    v = fmaxf(v, fmaxf(acc3[m][n][2 * p + 1] + bias, 0.f));
                    float v2 = fmaxf(v, __shfl_xor(v, 32));
                    if (lane < 32) {
                        int wq = (q & 1) * 2 + p;
                        o3[(size_t)b * 2048 + (m * 4 + wq) * 128 + ocb + n * 16 + lr] = f2bu(v2);
                    }
                }
            }
        }
    }
}

// ---------------------------------------------------------------------------
// K5: fc (2048->10, NCHW flatten) + log_softmax. One wave/image.
// ---------------------------------------------------------------------------
__global__ __launch_bounds__(256) void k_fc(
    const u16* __restrict__ o3, const float* __restrict__ fw,
    const float* __restrict__ fb, float* __restrict__ out)
{
    const int b = blockIdx.x * 4 + (threadIdx.x >> 6);
    const int lane = threadIdx.x & 63;
    const u16* xp = o3 + (size_t)b * 2048;
    float xr[32];
    #pragma unroll
    for (int i = 0; i < 32; ++i) {
        int kk = lane + i * 64;
        int c = kk >> 4, h = (kk >> 2) & 3, w = kk & 3;
        xr[i] = bu2f(xp[h * 512 + w * 128 + c]);
    }
    float lg[10];
    #pragma unroll
    for (int o = 0; o < 10; ++o) {
        const float* wr = fw + (size_t)o * 2048;
        float s = 0.f;
        #pragma unroll
        for (int i = 0; i < 32; ++i) s += xr[i] * wr[lane + i * 64];
        #pragma unroll
        for (int d = 32; d > 0; d >>= 1) s += __shfl_xor(s, d);
        lg[o] = s + fb[o];
    }
    float m = lg[0];
    #pragma unroll
    for (int o = 1; o < 10; ++o) m = fmaxf(m, lg[o]);
    float den = 0.f;
    #pragma unroll
    for (int o = 0; o < 10; ++o) den += expf(lg[o] - m);
    float lse = logf(den);
    if (lane < 10) {
        float v = lg[0];
        #pragma unroll
        for (int o = 1; o < 10; ++o) v = (lane == o) ? lg[o] : v;
        out[(size_t)b * 10 + lane] = v - m - lse;
    }
}

extern "C" void kernel_launch(void* const* d_in, const int* in_sizes, int n_in,
                              void* d_out, int out_size, void* d_ws, size_t ws_size,
                              hipStream_t stream)
{
    const float* x    = (const float*)d_in[0];
    const float* Wlin = (const float*)d_in[1];
    const float* c1w  = (const float*)d_in[2];
    const float* c1b  = (const float*)d_in[3];
    const float* c2w  = (const float*)d_in[4];
    const float* c2b  = (const float*)d_in[5];
    const float* c3w  = (const float*)d_in[6];
    const float* c3b  = (const float*)d_in[7];
    const float* fw   = (const float*)d_in[8];
    const float* fb   = (const float*)d_in[9];
    const int* stage  = (const int*)d_in[10];
    float* out = (float*)d_out;

    const int B = in_sizes[0] / 3072;      // 8192

    char* ws = (char*)d_ws;
    u16* o1   = (u16*)ws;
    u16* o3   = (u16*)(ws + (size_t)B * 24576);
    char* WB  = ws + (size_t)B * 28672;
    u16* w1p  = (u16*)(WB);
    u16* s2wp = (u16*)(WB + 4608);
    u16* w2p  = (u16*)(WB + 18432);
    u16* w3p  = (u16*)(WB + 56320);

    k_repack<<<288, 256, 0, stream>>>(Wlin, c1w, c2w, c3w, w1p, s2wp, w2p, w3p);
    k_front <<<B, 256, 0, stream>>>(x, s2wp, w1p, c1b, stage, o1);
    k_conv23<<<B, 256, 0, stream>>>(o1, w2p, c2b, w3p, c3b, o3);
    k_fc    <<<B / 4, 256, 0, stream>>>(o3, fw, fb, out);
}

// Round 14
// 306.417 us; speedup vs baseline: 1.6888x; 1.6888x over previous
//
#include <hip/hip_runtime.h>
#include <hip/hip_bf16.h>

typedef unsigned short u16;   // bf16 bits
typedef __attribute__((ext_vector_type(8))) short short8v;   // 8 bf16 (4 VGPRs)
typedef __attribute__((ext_vector_type(4))) float f32x4;
typedef union { short8v v; uint u[4]; } pack8;

__device__ __forceinline__ float bu2f(u16 u) {
    return __uint_as_float(((unsigned)u) << 16);
}
__device__ __forceinline__ u16 f2bu(float f) {   // RNE f32->bf16
    unsigned u = __float_as_uint(f);
    u += 0x7fffu + ((u >> 16) & 1u);
    return (u16)(u >> 16);
}
__device__ __forceinline__ uint pk2(float a, float b) {
    return (uint)f2bu(a) | ((uint)f2bu(b) << 16);
}

// ---------------------------------------------------------------------------
// K-repack: all weights -> MFMA-friendly bf16 layouts in ws (unchanged).
//  w1p  [32][72]: k = kh*16 + kw*3 + c (zeros elsewhere)         conv1
//  s2wp [96][72]: rows 0-47 W_lin hi, 48-95 W_lin lo; k<48 valid stage2
//  w2p  [64][296]: k = tap*32 + ic                               conv2
//  w3p  [128][584]: k = tap*64 + ic                              conv3
// ---------------------------------------------------------------------------
__global__ __launch_bounds__(256) void k_repack(
    const float* __restrict__ Wlin, const float* __restrict__ c1w,
    const float* __restrict__ c2w, const float* __restrict__ c3w,
    u16* __restrict__ w1p, u16* __restrict__ s2wp,
    u16* __restrict__ w2p, u16* __restrict__ w3p)
{
    int i = blockIdx.x * 256 + threadIdx.x;
    if (i < 32 * 72) {
        int oc = i / 72, k = i - oc * 72;
        int kh = k >> 4, e = k & 15;
        u16 v = 0;
        if (kh < 3 && e < 9) {
            int kw = e / 3, c = e - kw * 3;
            v = f2bu(c1w[((oc * 3 + c) * 3 + kh) * 3 + kw]);
        }
        w1p[i] = v;
    }
    if (i < 96 * 72) {
        int r = i / 72, k = i - r * 72;
        u16 v = 0;
        if (k < 48) {
            int o = r % 48;
            float w = Wlin[o * 48 + k];
            u16 hi = f2bu(w);
            v = (r < 48) ? hi : f2bu(w - bu2f(hi));
        }
        s2wp[i] = v;
    }
    if (i < 64 * 288) {
        int oc = i / 288, r = i - oc * 288;
        int tap = r >> 5, ic = r & 31;
        w2p[oc * 296 + r] = f2bu(c2w[(oc * 32 + ic) * 9 + tap]);
    }
    if (i < 128 * 576) {
        int oc = i / 576, r = i - oc * 576;
        int tap = r >> 6, ic = r & 63;
        w3p[oc * 584 + r] = f2bu(c3w[(oc * 64 + ic) * 9 + tap]);
    }
}

// ---------------------------------------------------------------------------
// K-img: FULL per-image pipeline: stage2 -> conv1 -> conv2 -> conv3.
// Fusion of the proven k_front (r3-r8) and k_conv23 v2 (r9) phase code.
// o1 never touches HBM: conv1's epilogue writes pooled output straight into
// in2's LDS layout. o2 already LDS-only (in3). Only x is read, o3 written.
//
// LDS map (u16 idx), phase-overlapped:
//   imgE [0,3488) imgO [3488,6976)       stage2 out / conv1 in
//   XB   [6976,11584)  S2W [11584,18496) stage2 A / W (dead after stage2)
//   IN3  [6976,13376)                    overlays XB+S2W head; zeroed in
//                                        conv1 phase, written by conv2 epi
//   W1L  [18496,20800)                   conv1 weights
//   IN2  [20800,33760)                   [18][18][40], conv1 epi -> conv2 A
// Total 33760 u16 = 67.5 KB -> 2 WG/CU (8 waves/CU, same residency as r8/r9).
// No launch bounds (r7/r11/r12 lessons: let allocator pick; acc caps waves).
// ---------------------------------------------------------------------------
#define IMG_E 0
#define IMG_O 3488
#define XB    6976
#define S2W   11584
#define IN3   6976
#define W1L   18496
#define IN2   20800
#define LDS_N 33760

__global__ __launch_bounds__(256) void k_img(
    const float* __restrict__ x, const u16* __restrict__ s2wp,
    const u16* __restrict__ w1p, const float* __restrict__ c1b,
    const int* __restrict__ stage,
    const u16* __restrict__ w2p, const float* __restrict__ c2b,
    const u16* __restrict__ w3p, const float* __restrict__ c3b,
    u16* __restrict__ o3)
{
    __shared__ __align__(16) u16 lds[LDS_N];
    const int b = blockIdx.x, t = threadIdx.x;
    const int wv = t >> 6, lane = t & 63, lr = lane & 15, q = lane >> 4;
    uint* z32 = (uint*)lds;

    // ---- P0: zero imgE/imgO + in2; load stage2/conv1 weights ----
    for (int i = t; i < 3488; i += 256) z32[i] = 0u;
    for (int i = t; i < 6480; i += 256) z32[10400 + i] = 0u;     // IN2/2 = 10400
    for (int i = t; i < 864; i += 256)
        *(short8v*)(&lds[S2W + i * 8]) = *(const short8v*)(&s2wp[i * 8]);
    for (int i = t; i < 288; i += 256)
        *(short8v*)(&lds[W1L + i * 8]) = *(const short8v*)(&w1p[i * 8]);

    const int sv = stage[0];
    if (sv == 2) {
        {   // build xb: thread t -> block n = t>>2, row ir = t&3
            const int n = t >> 2, ir = t & 3;
            const float* xp = x + (size_t)b * 3072 + (((n >> 3) * 4 + ir) * 96 + (n & 7) * 12);
            const float4 va = ((const float4*)xp)[0];
            const float4 vb = ((const float4*)xp)[1];
            const float4 vc = ((const float4*)xp)[2];
            uint* dst = (uint*)&lds[XB + n * 72 + ir * 12];
            dst[0] = pk2(va.x, va.y); dst[1] = pk2(va.z, va.w);
            dst[2] = pk2(vb.x, vb.y); dst[3] = pk2(vb.z, vb.w);
            dst[4] = pk2(vc.x, vc.y); dst[5] = pk2(vc.z, vc.w);
            if (ir < 2) {
                uint* z2 = (uint*)&lds[XB + n * 72 + 48 + ir * 8];
                z2[0] = 0u; z2[1] = 0u; z2[2] = 0u; z2[3] = 0u;
            }
        }
        __syncthreads();
        short8v a0 = *(const short8v*)&lds[XB + (wv * 16 + lr) * 72 + q * 8];
        short8v a1 = *(const short8v*)&lds[XB + (wv * 16 + lr) * 72 + 32 + q * 8];
        f32x4 y[3];
        #pragma unroll
        for (int nf = 0; nf < 3; ++nf) {
            y[nf] = (f32x4){0.f, 0.f, 0.f, 0.f};
            short8v bh0 = *(const short8v*)&lds[S2W + (nf * 16 + lr) * 72 + q * 8];
            short8v bh1 = *(const short8v*)&lds[S2W + (nf * 16 + lr) * 72 + 32 + q * 8];
            short8v bl0 = *(const short8v*)&lds[S2W + (48 + nf * 16 + lr) * 72 + q * 8];
            short8v bl1 = *(const short8v*)&lds[S2W + (48 + nf * 16 + lr) * 72 + 32 + q * 8];
            y[nf] = __builtin_amdgcn_mfma_f32_16x16x32_bf16(a0, bh0, y[nf], 0, 0, 0);
            y[nf] = __builtin_amdgcn_mfma_f32_16x16x32_bf16(a1, bh1, y[nf], 0, 0, 0);
            y[nf] = __builtin_amdgcn_mfma_f32_16x16x32_bf16(a0, bl0, y[nf], 0, 0, 0);
            y[nf] = __builtin_amdgcn_mfma_f32_16x16x32_bf16(a1, bl1, y[nf], 0, 0, 0);
        }
        __syncthreads();     // img zero complete + XB/S2W reads done
        #pragma unroll
        for (int nf = 0; nf < 3; ++nf)
            #pragma unroll
            for (int r = 0; r < 4; ++r) {
                int n2 = wv * 16 + q * 4 + r;
                int o  = nf * 16 + lr;
                int ir = o / 12, rm = o - ir * 12;
                int jc = rm / 3, c = rm - jc * 3;
                int hh = (n2 >> 3) * 4 + ir, ww = (n2 & 7) * 4 + jc;
                int e  = ((hh + 1) * 34 + (ww + 1)) * 3 + c;
                u16 val = f2bu(y[nf][r]);
                lds[IMG_E + e] = val;
                lds[IMG_O + e - 1] = val;
            }
    } else {
        __syncthreads();
        for (int e = t; e < 3072; e += 256) {
            int hh = e / 96, rm = e - hh * 96;
            int ww = rm / 3, c = rm - ww * 3;
            u16 val = f2bu(x[(size_t)b * 3072 + e]);
            int ii = ((hh + 1) * 34 + (ww + 1)) * 3 + c;
            lds[IMG_E + ii] = val;
            lds[IMG_O + ii - 1] = val;
        }
    }
    __syncthreads();

    // ---- P2: conv1 (MFMA) -> in2 LDS; also zero IN3 (overlays dead XB/S2W) ----
    for (int i = t; i < 3200; i += 256) z32[3488 + i] = 0u;      // IN3/2 = 3488
    {
        short8v wf[2][2];
        #pragma unroll
        for (int nf = 0; nf < 2; ++nf)
            #pragma unroll
            for (int ks = 0; ks < 2; ++ks)
                wf[nf][ks] = *(const short8v*)&lds[W1L + (nf * 16 + lr) * 72 + ks * 32 + q * 8];
        const float bias[2] = {c1b[lr], c1b[16 + lr]};

        #pragma unroll
        for (int mc = 0; mc < 4; ++mc) {
            f32x4 acc[4][2];
            #pragma unroll
            for (int mi = 0; mi < 4; ++mi)
                #pragma unroll
                for (int nf = 0; nf < 2; ++nf) acc[mi][nf] = (f32x4){0.f, 0.f, 0.f, 0.f};
            #pragma unroll
            for (int mi = 0; mi < 4; ++mi) {
                const int p = wv * 256 + (mc * 4 + mi) * 16 + lr;
                const int ph = p >> 5, pw = p & 31;
                #pragma unroll
                for (int ks = 0; ks < 2; ++ks) {
                    const int r = ks ? 2 : (q >> 1);
                    const int a = 3 * ((ph + r) * 34 + pw) + (q & 1) * 8;
                    const uint* sp = (a & 1) ? (const uint*)&lds[IMG_O + a - 1]
                                             : (const uint*)&lds[IMG_E + a];
                    pack8 pk;
                    pk.u[0] = sp[0]; pk.u[1] = sp[1]; pk.u[2] = sp[2]; pk.u[3] = sp[3];
                    acc[mi][0] = __builtin_amdgcn_mfma_f32_16x16x32_bf16(pk.v, wf[0][ks], acc[mi][0], 0, 0, 0);
                    acc[mi][1] = __builtin_amdgcn_mfma_f32_16x16x32_bf16(pk.v, wf[1][ks], acc[mi][1], 0, 0, 0);
                }
            }
            // epilogue: relu+bias+pool -> in2 (padded LDS layout, halo pre-zeroed)
            #pragma unroll
            for (int pr = 0; pr < 2; ++pr)
                #pragma unroll
                for (int nf = 0; nf < 2; ++nf) {
                    const float bb = bias[nf];
                    #pragma unroll
                    for (int j = 0; j < 2; ++j) {
                        float v = fmaxf(acc[pr][nf][2 * j] + bb, 0.f);
                        v = fmaxf(v, fmaxf(acc[pr][nf][2 * j + 1] + bb, 0.f));
                        v = fmaxf(v, fmaxf(acc[pr + 2][nf][2 * j] + bb, 0.f));
                        v = fmaxf(v, fmaxf(acc[pr + 2][nf][2 * j + 1] + bb, 0.f));
                        const int hq = wv * 4 + mc, wq = pr * 8 + q * 2 + j;
                        lds[IN2 + ((hq + 1) * 18 + (wq + 1)) * 40 + nf * 16 + lr] = f2bu(v);
                    }
                }
        }
    }
    __syncthreads();     // in2 complete, IN3 zeroed

    // ---- P3: conv2 (r9 code): B depth-2 global ring, A from in2 ----
    {
        const u16* wb2 = w2p + (size_t)lr * 296 + q * 8;
        f32x4 acc[4][4];
        #pragma unroll
        for (int m = 0; m < 4; ++m)
            #pragma unroll
            for (int n = 0; n < 4; ++n) acc[m][n] = (f32x4){0.f, 0.f, 0.f, 0.f};

        short8v bfr[3][4];
        #pragma unroll
        for (int n = 0; n < 4; ++n) {
            bfr[0][n] = *(const short8v*)(wb2 + n * 4736 + 0);
            bfr[1][n] = *(const short8v*)(wb2 + n * 4736 + 32);
        }
        #pragma unroll
        for (int s = 0; s < 9; ++s) {
            if (s + 2 < 9) {
                #pragma unroll
                for (int n = 0; n < 4; ++n)
                    bfr[(s + 2) % 3][n] = *(const short8v*)(wb2 + n * 4736 + (s + 2) * 32);
            }
            const int kh = s / 3, kw = s - kh * 3;
            short8v af[4];
            #pragma unroll
            for (int m = 0; m < 4; ++m)
                af[m] = *(const short8v*)(&lds[IN2 + ((wv * 4 + m + kh) * 18 + lr + kw) * 40 + q * 8]);
            #pragma unroll
            for (int m = 0; m < 4; ++m)
                #pragma unroll
                for (int n = 0; n < 4; ++n)
                    acc[m][n] = __builtin_amdgcn_mfma_f32_16x16x32_bf16(af[m], bfr[s % 3][n], acc[m][n], 0, 0, 0);
        }
        // epilogue: bias+relu+pool -> in3 (swizzled), halo stays zero
        #pragma unroll
        for (int n = 0; n < 4; ++n) {
            float bias = c2b[n * 16 + lr];
            #pragma unroll
            for (int mp = 0; mp < 2; ++mp) {
                #pragma unroll
                for (int p = 0; p < 2; ++p) {
                    float v = fmaxf(acc[2 * mp][n][2 * p] + bias, 0.f);
                    v = fmaxf(v, fmaxf(acc[2 * mp][n][2 * p + 1] + bias, 0.f));
                    v = fmaxf(v, fmaxf(acc[2 * mp + 1][n][2 * p] + bias, 0.f));
                    v = fmaxf(v, fmaxf(acc[2 * mp + 1][n][2 * p + 1] + bias, 0.f));
                    int hq = wv * 2 + mp, wq = 2 * q + p;
                    int posW = (hq + 1) * 10 + (wq + 1);
                    int oc = n * 16 + lr;
                    lds[IN3 + posW * 64 + (oc ^ ((posW & 7) << 3))] = f2bu(v);
                }
            }
        }
    }
    __syncthreads();     // in3 complete

    // ---- P4: conv3 (r9 code): wave wv -> oc block wv*32, B depth-2 ring ----
    {
        const int ocb = wv * 32;
        const int hA = lr >> 3, wA = lr & 7;
        const u16* wb3 = w3p + (size_t)(ocb + lr) * 584 + q * 8;

        f32x4 acc3[4][2];
        #pragma unroll
        for (int m = 0; m < 4; ++m)
            #pragma unroll
            for (int n = 0; n < 2; ++n) acc3[m][n] = (f32x4){0.f, 0.f, 0.f, 0.f};

        short8v br[3][2];
        #pragma unroll
        for (int n = 0; n < 2; ++n) {
            br[0][n] = *(const short8v*)(wb3 + n * 9344 + 0);
            br[1][n] = *(const short8v*)(wb3 + n * 9344 + 32);
        }
        #pragma unroll
        for (int s = 0; s < 18; ++s) {
            if (s + 2 < 18) {
                const int off2 = ((s + 2) >> 1) * 64 + ((s + 2) & 1) * 32;
                #pragma unroll
                for (int n = 0; n < 2; ++n)
                    br[(s + 2) % 3][n] = *(const short8v*)(wb3 + n * 9344 + off2);
            }
            const int tap = s >> 1, half = s & 1;
            const int kh = tap / 3, kw = tap - kh * 3;
            short8v a3[4];
            #pragma unroll
            for (int m = 0; m < 4; ++m) {
                int posR = (m * 2 + hA + kh) * 10 + wA + kw;
                int sl = (half * 32 + q * 8) ^ ((posR & 7) << 3);
                a3[m] = *(const short8v*)(&lds[IN3 + posR * 64 + sl]);
            }
            #pragma unroll
            for (int m = 0; m < 4; ++m)
                #pragma unroll
                for (int n = 0; n < 2; ++n)
                    acc3[m][n] = __builtin_amdgcn_mfma_f32_16x16x32_bf16(a3[m], br[s % 3][n], acc3[m][n], 0, 0, 0);
        }
        #pragma unroll
        for (int n = 0; n < 2; ++n) {
            float bias = c3b[ocb + n * 16 + lr];
            #pragma unroll
            for (int m = 0; m < 4; ++m) {
                #pragma unroll
                for (int p = 0; p < 2; ++p) {
                    float v = fmaxf(acc3[m][n][2 * p] + bias, 0.f);
                    v = fmaxf(v, fmaxf(acc3[m][n][2 * p + 1] + bias, 0.f));
                    float v2 = fmaxf(v, __shfl_xor(v, 32));
                    if (lane < 32) {
                        int wq = (q & 1) * 2 + p;
                        o3[(size_t)b * 2048 + (m * 4 + wq) * 128 + ocb + n * 16 + lr] = f2bu(v2);
                    }
                }
            }
        }
    }
}

// ---------------------------------------------------------------------------
// K5: fc (2048->10, NCHW flatten) + log_softmax. One wave/image (unchanged).
// ---------------------------------------------------------------------------
__global__ __launch_bounds__(256) void k_fc(
    const u16* __restrict__ o3, const float* __restrict__ fw,
    const float* __restrict__ fb, float* __restrict__ out)
{
    const int b = blockIdx.x * 4 + (threadIdx.x >> 6);
    const int lane = threadIdx.x & 63;
    const u16* xp = o3 + (size_t)b * 2048;
    float xr[32];
    #pragma unroll
    for (int i = 0; i < 32; ++i) {
        int kk = lane + i * 64;
        int c = kk >> 4, h = (kk >> 2) & 3, w = kk & 3;
        xr[i] = bu2f(xp[h * 512 + w * 128 + c]);
    }
    float lg[10];
    #pragma unroll
    for (int o = 0; o < 10; ++o) {
        const float* wr = fw + (size_t)o * 2048;
        float s = 0.f;
        #pragma unroll
        for (int i = 0; i < 32; ++i) s += xr[i] * wr[lane + i * 64];
        #pragma unroll
        for (int d = 32; d > 0; d >>= 1) s += __shfl_xor(s, d);
        lg[o] = s + fb[o];
    }
    float m = lg[0];
    #pragma unroll
    for (int o = 1; o < 10; ++o) m = fmaxf(m, lg[o]);
    float den = 0.f;
    #pragma unroll
    for (int o = 0; o < 10; ++o) den += expf(lg[o] - m);
    float lse = logf(den);
    if (lane < 10) {
        float v = lg[0];
        #pragma unroll
        for (int o = 1; o < 10; ++o) v = (lane == o) ? lg[o] : v;
        out[(size_t)b * 10 + lane] = v - m - lse;
    }
}

extern "C" void kernel_launch(void* const* d_in, const int* in_sizes, int n_in,
                              void* d_out, int out_size, void* d_ws, size_t ws_size,
                              hipStream_t stream)
{
    const float* x    = (const float*)d_in[0];
    const float* Wlin = (const float*)d_in[1];
    const float* c1w  = (const float*)d_in[2];
    const float* c1b  = (const float*)d_in[3];
    const float* c2w  = (const float*)d_in[4];
    const float* c2b  = (const float*)d_in[5];
    const float* c3w  = (const float*)d_in[6];
    const float* c3b  = (const float*)d_in[7];
    const float* fw   = (const float*)d_in[8];
    const float* fb   = (const float*)d_in[9];
    const int* stage  = (const int*)d_in[10];
    float* out = (float*)d_out;

    const int B = in_sizes[0] / 3072;      // 8192

    // ws: o3 [0, B*4096 B) ; weights after.
    char* ws = (char*)d_ws;
    u16* o3   = (u16*)ws;
    char* WB  = ws + (size_t)B * 4096;
    u16* w1p  = (u16*)(WB);
    u16* s2wp = (u16*)(WB + 4608);
    u16* w2p  = (u16*)(WB + 18432);
    u16* w3p  = (u16*)(WB + 56320);

    k_repack<<<288, 256, 0, stream>>>(Wlin, c1w, c2w, c3w, w1p, s2wp, w2p, w3p);
    k_img   <<<B, 256, 0, stream>>>(x, s2wp, w1p, c1b, stage, w2p, c2b, w3p, c3b, o3);
    k_fc    <<<B / 4, 256, 0, stream>>>(o3, fw, fb, out);
}

// Round 15
// 287.384 us; speedup vs baseline: 1.8006x; 1.0662x over previous
//
#include <hip/hip_runtime.h>
#include <hip/hip_bf16.h>

typedef unsigned short u16;   // bf16 bits
typedef __attribute__((ext_vector_type(8))) short short8v;   // 8 bf16 (4 VGPRs)
typedef __attribute__((ext_vector_type(4))) float f32x4;
typedef __attribute__((ext_vector_type(16))) float f32x16;
typedef union { short8v v; uint u[4]; } pack8;

__device__ __forceinline__ float bu2f(u16 u) {
    return __uint_as_float(((unsigned)u) << 16);
}
__device__ __forceinline__ u16 f2bu(float f) {   // RNE f32->bf16
    unsigned u = __float_as_uint(f);
    u += 0x7fffu + ((u >> 16) & 1u);
    return (u16)(u >> 16);
}
__device__ __forceinline__ uint pk2(float a, float b) {
    return (uint)f2bu(a) | ((uint)f2bu(b) << 16);
}

// ---------------------------------------------------------------------------
// K-repack: all weights -> MFMA-friendly bf16 layouts in ws (unchanged).
//  w1p  [32][72]: k = kh*16 + kw*3 + c (zeros elsewhere)         conv1
//  s2wp [96][72]: rows 0-47 W_lin hi, 48-95 W_lin lo; k<48 valid stage2
//  w2p  [64][296]: k = tap*32 + ic                               conv2
//  w3p  [128][584]: k = tap*64 + ic                              conv3
// ---------------------------------------------------------------------------
__global__ __launch_bounds__(256) void k_repack(
    const float* __restrict__ Wlin, const float* __restrict__ c1w,
    const float* __restrict__ c2w, const float* __restrict__ c3w,
    u16* __restrict__ w1p, u16* __restrict__ s2wp,
    u16* __restrict__ w2p, u16* __restrict__ w3p)
{
    int i = blockIdx.x * 256 + threadIdx.x;
    if (i < 32 * 72) {
        int oc = i / 72, k = i - oc * 72;
        int kh = k >> 4, e = k & 15;
        u16 v = 0;
        if (kh < 3 && e < 9) {
            int kw = e / 3, c = e - kw * 3;
            v = f2bu(c1w[((oc * 3 + c) * 3 + kh) * 3 + kw]);
        }
        w1p[i] = v;
    }
    if (i < 96 * 72) {
        int r = i / 72, k = i - r * 72;
        u16 v = 0;
        if (k < 48) {
            int o = r % 48;
            float w = Wlin[o * 48 + k];
            u16 hi = f2bu(w);
            v = (r < 48) ? hi : f2bu(w - bu2f(hi));
        }
        s2wp[i] = v;
    }
    if (i < 64 * 288) {
        int oc = i / 288, r = i - oc * 288;
        int tap = r >> 5, ic = r & 31;
        w2p[oc * 296 + r] = f2bu(c2w[(oc * 32 + ic) * 9 + tap]);
    }
    if (i < 128 * 576) {
        int oc = i / 576, r = i - oc * 576;
        int tap = r >> 6, ic = r & 63;
        w3p[oc * 584 + r] = f2bu(c3w[(oc * 64 + ic) * 9 + tap]);
    }
}

// ---------------------------------------------------------------------------
// K-img: FULL per-image pipeline: stage2 -> conv1 -> conv2 -> conv3.
// v2 changes vs r14: conv1 uses 32x32x16 MFMA (3 K-steps over K=48; MFMA
// issue -25%, A b32 reads 128->96, B reads 16->3; both pool pairs reg-local
// in the 32x32 C-layout col=lane&31,row=(reg&3)+8*(reg>>2)+4*(lane>>5));
// halo-only zeroing for in2/in3; s_setprio(1) around conv2/conv3 MFMA.
// LDS map unchanged: imgE/imgO | XB/S2W (overlaid by IN3) | W1L | IN2.
// 67.5 KB -> 2 WG/CU.
// ---------------------------------------------------------------------------
#define IMG_E 0
#define IMG_O 3488
#define XB    6976
#define S2W   11584
#define IN3   6976
#define W1L   18496
#define IN2   20800
#define LDS_N 33760

__global__ __launch_bounds__(256) void k_img(
    const float* __restrict__ x, const u16* __restrict__ s2wp,
    const u16* __restrict__ w1p, const float* __restrict__ c1b,
    const int* __restrict__ stage,
    const u16* __restrict__ w2p, const float* __restrict__ c2b,
    const u16* __restrict__ w3p, const float* __restrict__ c3b,
    u16* __restrict__ o3)
{
    __shared__ __align__(16) u16 lds[LDS_N];
    const int b = blockIdx.x, t = threadIdx.x;
    const int wv = t >> 6, lane = t & 63, lr = lane & 15, q = lane >> 4;
    uint* z32 = (uint*)lds;

    // ---- P0: zero imgE/imgO fully (garbage-window safety) + in2 HALO only ----
    for (int i = t; i < 3488; i += 256) z32[i] = 0u;
    for (int i = t; i < 1360; i += 256) {            // in2 halo: 68 cells x 20 dw
        int cell = i / 20, d = i - cell * 20;
        int h, w;
        if (cell < 18)      { h = 0;  w = cell; }
        else if (cell < 36) { h = 17; w = cell - 18; }
        else { int k = cell - 36; h = 1 + (k >> 1); w = (k & 1) * 17; }
        z32[10400 + (h * 18 + w) * 20 + d] = 0u;     // IN2/2 = 10400
    }
    for (int i = t; i < 864; i += 256)
        *(short8v*)(&lds[S2W + i * 8]) = *(const short8v*)(&s2wp[i * 8]);
    for (int i = t; i < 288; i += 256)
        *(short8v*)(&lds[W1L + i * 8]) = *(const short8v*)(&w1p[i * 8]);

    const int sv = stage[0];
    if (sv == 2) {
        {   // build xb: thread t -> block n = t>>2, row ir = t&3
            const int n = t >> 2, ir = t & 3;
            const float* xp = x + (size_t)b * 3072 + (((n >> 3) * 4 + ir) * 96 + (n & 7) * 12);
            const float4 va = ((const float4*)xp)[0];
            const float4 vb = ((const float4*)xp)[1];
            const float4 vc = ((const float4*)xp)[2];
            uint* dst = (uint*)&lds[XB + n * 72 + ir * 12];
            dst[0] = pk2(va.x, va.y); dst[1] = pk2(va.z, va.w);
            dst[2] = pk2(vb.x, vb.y); dst[3] = pk2(vb.z, vb.w);
            dst[4] = pk2(vc.x, vc.y); dst[5] = pk2(vc.z, vc.w);
            if (ir < 2) {
                uint* z2 = (uint*)&lds[XB + n * 72 + 48 + ir * 8];
                z2[0] = 0u; z2[1] = 0u; z2[2] = 0u; z2[3] = 0u;
            }
        }
        __syncthreads();
        short8v a0 = *(const short8v*)&lds[XB + (wv * 16 + lr) * 72 + q * 8];
        short8v a1 = *(const short8v*)&lds[XB + (wv * 16 + lr) * 72 + 32 + q * 8];
        f32x4 y[3];
        #pragma unroll
        for (int nf = 0; nf < 3; ++nf) {
            y[nf] = (f32x4){0.f, 0.f, 0.f, 0.f};
            short8v bh0 = *(const short8v*)&lds[S2W + (nf * 16 + lr) * 72 + q * 8];
            short8v bh1 = *(const short8v*)&lds[S2W + (nf * 16 + lr) * 72 + 32 + q * 8];
            short8v bl0 = *(const short8v*)&lds[S2W + (48 + nf * 16 + lr) * 72 + q * 8];
            short8v bl1 = *(const short8v*)&lds[S2W + (48 + nf * 16 + lr) * 72 + 32 + q * 8];
            y[nf] = __builtin_amdgcn_mfma_f32_16x16x32_bf16(a0, bh0, y[nf], 0, 0, 0);
            y[nf] = __builtin_amdgcn_mfma_f32_16x16x32_bf16(a1, bh1, y[nf], 0, 0, 0);
            y[nf] = __builtin_amdgcn_mfma_f32_16x16x32_bf16(a0, bl0, y[nf], 0, 0, 0);
            y[nf] = __builtin_amdgcn_mfma_f32_16x16x32_bf16(a1, bl1, y[nf], 0, 0, 0);
        }
        __syncthreads();     // img zero complete + XB/S2W reads done
        #pragma unroll
        for (int nf = 0; nf < 3; ++nf)
            #pragma unroll
            for (int r = 0; r < 4; ++r) {
                int n2 = wv * 16 + q * 4 + r;
                int o  = nf * 16 + lr;
                int ir = o / 12, rm = o - ir * 12;
                int jc = rm / 3, c = rm - jc * 3;
                int hh = (n2 >> 3) * 4 + ir, ww = (n2 & 7) * 4 + jc;
                int e  = ((hh + 1) * 34 + (ww + 1)) * 3 + c;
                u16 val = f2bu(y[nf][r]);
                lds[IMG_E + e] = val;
                lds[IMG_O + e - 1] = val;
            }
    } else {
        __syncthreads();
        for (int e = t; e < 3072; e += 256) {
            int hh = e / 96, rm = e - hh * 96;
            int ww = rm / 3, c = rm - ww * 3;
            u16 val = f2bu(x[(size_t)b * 3072 + e]);
            int ii = ((hh + 1) * 34 + (ww + 1)) * 3 + c;
            lds[IMG_E + ii] = val;
            lds[IMG_O + ii - 1] = val;
        }
    }
    __syncthreads();

    // ---- P2: conv1 via 32x32x16 MFMA -> in2 LDS; zero IN3 halo (XB/S2W dead) ----
    for (int i = t; i < 1152; i += 256) {            // in3 halo: 36 cells x 32 dw
        int cell = i >> 5, d = i & 31;
        int pos;
        if (cell < 10)      pos = cell;              // ph = 0
        else if (cell < 20) pos = 90 + (cell - 10);  // ph = 9
        else { int k = cell - 20; pos = (1 + (k >> 1)) * 10 + (k & 1) * 9; }
        z32[3488 + pos * 32 + d] = 0u;               // IN3/2 = 3488
    }
    {
        const int oc32 = lane & 31, hi = lane >> 5;
        short8v wb[3];
        #pragma unroll
        for (int s = 0; s < 3; ++s)
            wb[s] = *(const short8v*)&lds[W1L + oc32 * 72 + s * 16 + hi * 8];
        const float bias1 = c1b[oc32];

        #pragma unroll
        for (int chk = 0; chk < 4; ++chk) {          // chunk = 2 h-rows
            f32x16 acc0, acc1;
            #pragma unroll
            for (int i = 0; i < 16; ++i) { acc0[i] = 0.f; acc1[i] = 0.f; }
            #pragma unroll
            for (int s = 0; s < 3; ++s) {
                #pragma unroll
                for (int f = 0; f < 2; ++f) {
                    const int h = wv * 8 + chk * 2 + f;
                    const int a = 3 * ((h + s) * 34 + oc32) + hi * 8;
                    const uint* sp = (a & 1) ? (const uint*)&lds[IMG_O + a - 1]
                                             : (const uint*)&lds[IMG_E + a];
                    pack8 pk;
                    pk.u[0] = sp[0]; pk.u[1] = sp[1]; pk.u[2] = sp[2]; pk.u[3] = sp[3];
                    if (f == 0) acc0 = __builtin_amdgcn_mfma_f32_32x32x16_bf16(pk.v, wb[s], acc0, 0, 0, 0);
                    else        acc1 = __builtin_amdgcn_mfma_f32_32x32x16_bf16(pk.v, wb[s], acc1, 0, 0, 0);
                }
            }
            // epilogue: rows (reg&3)+8*(reg>>2)+4*hi = w; h-pair = acc0/acc1.
            const int hq = wv * 4 + chk;
            #pragma unroll
            for (int g = 0; g < 4; ++g) {
                #pragma unroll
                for (int pp = 0; pp < 2; ++pp) {
                    float v = fmaxf(acc0[4 * g + 2 * pp] + bias1, 0.f);
                    v = fmaxf(v, fmaxf(acc0[4 * g + 2 * pp + 1] + bias1, 0.f));
                    v = fmaxf(v, fmaxf(acc1[4 * g + 2 * pp] + bias1, 0.f));
                    v = fmaxf(v, fmaxf(acc1[4 * g + 2 * pp + 1] + bias1, 0.f));
                    const int wq = 4 * g + 2 * hi + pp;
                    lds[IN2 + ((hq + 1) * 18 + (wq + 1)) * 40 + oc32] = f2bu(v);
                }
            }
        }
    }
    __syncthreads();     // in2 complete, IN3 halo zeroed

    // ---- P3: conv2 (r9 code): B depth-2 global ring, A from in2 ----
    {
        const u16* wb2 = w2p + (size_t)lr * 296 + q * 8;
        f32x4 acc[4][4];
        #pragma unroll
        for (int m = 0; m < 4; ++m)
            #pragma unroll
            for (int n = 0; n < 4; ++n) acc[m][n] = (f32x4){0.f, 0.f, 0.f, 0.f};

        short8v bfr[3][4];
        #pragma unroll
        for (int n = 0; n < 4; ++n) {
            bfr[0][n] = *(const short8v*)(wb2 + n * 4736 + 0);
            bfr[1][n] = *(const short8v*)(wb2 + n * 4736 + 32);
        }
        #pragma unroll
        for (int s = 0; s < 9; ++s) {
            if (s + 2 < 9) {
                #pragma unroll
                for (int n = 0; n < 4; ++n)
                    bfr[(s + 2) % 3][n] = *(const short8v*)(wb2 + n * 4736 + (s + 2) * 32);
            }
            const int kh = s / 3, kw = s - kh * 3;
            short8v af[4];
            #pragma unroll
            for (int m = 0; m < 4; ++m)
                af[m] = *(const short8v*)(&lds[IN2 + ((wv * 4 + m + kh) * 18 + lr + kw) * 40 + q * 8]);
            __builtin_amdgcn_s_setprio(1);
            #pragma unroll
            for (int m = 0; m < 4; ++m)
                #pragma unroll
                for (int n = 0; n < 4; ++n)
                    acc[m][n] = __builtin_amdgcn_mfma_f32_16x16x32_bf16(af[m], bfr[s % 3][n], acc[m][n], 0, 0, 0);
            __builtin_amdgcn_s_setprio(0);
        }
        // epilogue: bias+relu+pool -> in3 (swizzled), halo stays zero
        #pragma unroll
        for (int n = 0; n < 4; ++n) {
            float bias = c2b[n * 16 + lr];
            #pragma unroll
            for (int mp = 0; mp < 2; ++mp) {
                #pragma unroll
                for (int p = 0; p < 2; ++p) {
                    float v = fmaxf(acc[2 * mp][n][2 * p] + bias, 0.f);
                    v = fmaxf(v, fmaxf(acc[2 * mp][n][2 * p + 1] + bias, 0.f));
                    v = fmaxf(v, fmaxf(acc[2 * mp + 1][n][2 * p] + bias, 0.f));
                    v = fmaxf(v, fmaxf(acc[2 * mp + 1][n][2 * p + 1] + bias, 0.f));
                    int hq = wv * 2 + mp, wq = 2 * q + p;
                    int posW = (hq + 1) * 10 + (wq + 1);
                    int oc = n * 16 + lr;
                    lds[IN3 + posW * 64 + (oc ^ ((posW & 7) << 3))] = f2bu(v);
                }
            }
        }
    }
    __syncthreads();     // in3 complete

    // ---- P4: conv3 (r9 code): wave wv -> oc block wv*32, B depth-2 ring ----
    {
        const int ocb = wv * 32;
        const int hA = lr >> 3, wA = lr & 7;
        const u16* wb3 = w3p + (size_t)(ocb + lr) * 584 + q * 8;

        f32x4 acc3[4][2];
        #pragma unroll
        for (int m = 0; m < 4; ++m)
            #pragma unroll
            for (int n = 0; n < 2; ++n) acc3[m][n] = (f32x4){0.f, 0.f, 0.f, 0.f};

        short8v br[3][2];
        #pragma unroll
        for (int n = 0; n < 2; ++n) {
            br[0][n] = *(const short8v*)(wb3 + n * 9344 + 0);
            br[1][n] = *(const short8v*)(wb3 + n * 9344 + 32);
        }
        #pragma unroll
        for (int s = 0; s < 18; ++s) {
            if (s + 2 < 18) {
                const int off2 = ((s + 2) >> 1) * 64 + ((s + 2) & 1) * 32;
                #pragma unroll
                for (int n = 0; n < 2; ++n)
                    br[(s + 2) % 3][n] = *(const short8v*)(wb3 + n * 9344 + off2);
            }
            const int tap = s >> 1, half = s & 1;
            const int kh = tap / 3, kw = tap - kh * 3;
            short8v a3[4];
            #pragma unroll
            for (int m = 0; m < 4; ++m) {
                int posR = (m * 2 + hA + kh) * 10 + wA + kw;
                int sl = (half * 32 + q * 8) ^ ((posR & 7) << 3);
                a3[m] = *(const short8v*)(&lds[IN3 + posR * 64 + sl]);
            }
            __builtin_amdgcn_s_setprio(1);
            #pragma unroll
            for (int m = 0; m < 4; ++m)
                #pragma unroll
                for (int n = 0; n < 2; ++n)
                    acc3[m][n] = __builtin_amdgcn_mfma_f32_16x16x32_bf16(a3[m], br[s % 3][n], acc3[m][n], 0, 0, 0);
            __builtin_amdgcn_s_setprio(0);
        }
        #pragma unroll
        for (int n = 0; n < 2; ++n) {
            float bias = c3b[ocb + n * 16 + lr];
            #pragma unroll
            for (int m = 0; m < 4; ++m) {
                #pragma unroll
                for (int p = 0; p < 2; ++p) {
                    float v = fmaxf(acc3[m][n][2 * p] + bias, 0.f);
                    v = fmaxf(v, fmaxf(acc3[m][n][2 * p + 1] + bias, 0.f));
                    float v2 = fmaxf(v, __shfl_xor(v, 32));
                    if (lane < 32) {
                        int wq = (q & 1) * 2 + p;
                        o3[(size_t)b * 2048 + (m * 4 + wq) * 128 + ocb + n * 16 + lr] = f2bu(v2);
                    }
                }
            }
        }
    }
}

// ---------------------------------------------------------------------------
// K5: fc (2048->10, NCHW flatten) + log_softmax. One wave/image (unchanged).
// ---------------------------------------------------------------------------
__global__ __launch_bounds__(256) void k_fc(
    const u16* __restrict__ o3, const float* __restrict__ fw,
    const float* __restrict__ fb, float* __restrict__ out)
{
    const int b = blockIdx.x * 4 + (threadIdx.x >> 6);
    const int lane = threadIdx.x & 63;
    const u16* xp = o3 + (size_t)b * 2048;
    float xr[32];
    #pragma unroll
    for (int i = 0; i < 32; ++i) {
        int kk = lane + i * 64;
        int c = kk >> 4, h = (kk >> 2) & 3, w = kk & 3;
        xr[i] = bu2f(xp[h * 512 + w * 128 + c]);
    }
    float lg[10];
    #pragma unroll
    for (int o = 0; o < 10; ++o) {
        const float* wr = fw + (size_t)o * 2048;
        float s = 0.f;
        #pragma unroll
        for (int i = 0; i < 32; ++i) s += xr[i] * wr[lane + i * 64];
        #pragma unroll
        for (int d = 32; d > 0; d >>= 1) s += __shfl_xor(s, d);
        lg[o] = s + fb[o];
    }
    float m = lg[0];
    #pragma unroll
    for (int o = 1; o < 10; ++o) m = fmaxf(m, lg[o]);
    float den = 0.f;
    #pragma unroll
    for (int o = 0; o < 10; ++o) den += expf(lg[o] - m);
    float lse = logf(den);
    if (lane < 10) {
        float v = lg[0];
        #pragma unroll
        for (int o = 1; o < 10; ++o) v = (lane == o) ? lg[o] : v;
        out[(size_t)b * 10 + lane] = v - m - lse;
    }
}

extern "C" void kernel_launch(void* const* d_in, const int* in_sizes, int n_in,
                              void* d_out, int out_size, void* d_ws, size_t ws_size,
                              hipStream_t stream)
{
    const float* x    = (const float*)d_in[0];
    const float* Wlin = (const float*)d_in[1];
    const float* c1w  = (const float*)d_in[2];
    const float* c1b  = (const float*)d_in[3];
    const float* c2w  = (const float*)d_in[4];
    const float* c2b  = (const float*)d_in[5];
    const float* c3w  = (const float*)d_in[6];
    const float* c3b  = (const float*)d_in[7];
    const float* fw   = (const float*)d_in[8];
    const float* fb   = (const float*)d_in[9];
    const int* stage  = (const int*)d_in[10];
    float* out = (float*)d_out;

    const int B = in_sizes[0] / 3072;      // 8192

    // ws: o3 [0, B*4096 B) ; weights after.
    char* ws = (char*)d_ws;
    u16* o3   = (u16*)ws;
    char* WB  = ws + (size_t)B * 4096;
    u16* w1p  = (u16*)(WB);
    u16* s2wp = (u16*)(WB + 4608);
    u16* w2p  = (u16*)(WB + 18432);
    u16* w3p  = (u16*)(WB + 56320);

    k_repack<<<288, 256, 0, stream>>>(Wlin, c1w, c2w, c3w, w1p, s2wp, w2p, w3p);
    k_img   <<<B, 256, 0, stream>>>(x, s2wp, w1p, c1b, stage, w2p, c2b, w3p, c3b, o3);
    k_fc    <<<B / 4, 256, 0, stream>>>(o3, fw, fb, out);
}